// Round 1
// baseline (356.025 us; speedup 1.0000x reference)
//
#include <hip/hip_runtime.h>
#include <hip/hip_bf16.h>
#include <stdint.h>

typedef unsigned short u16;

#define Bdim 8
#define Ldim 2048
#define Ddim 1024
#define NH 16
#define HD 64
#define MTOK (Bdim*Ldim)   // 16384

#define BM 128
#define BN 128
#define BK 32

typedef __bf16 bf16x8 __attribute__((ext_vector_type(8)));
typedef float  f32x4  __attribute__((ext_vector_type(4)));

#define AS1 __attribute__((address_space(1)))
#define AS3 __attribute__((address_space(3)))

__device__ __forceinline__ void gload_lds16(const void* g, void* l) {
  __builtin_amdgcn_global_load_lds((const AS1 void*)g, (AS3 void*)l, 16, 0, 0);
}

__device__ __forceinline__ u16 f2bf(float f) {
  uint32_t u = __builtin_bit_cast(uint32_t, f);
  u += 0x7fffu + ((u >> 16) & 1u);   // round-to-nearest-even
  return (u16)(u >> 16);
}
__device__ __forceinline__ float bf2f(u16 u) {
  uint32_t x = ((uint32_t)u) << 16;
  return __builtin_bit_cast(float, x);
}

// ---------------- fp32 -> bf16 convert (vectorized, 4 elems/thread) ----------
__global__ __launch_bounds__(256) void conv_f32_bf16(const float* __restrict__ in,
                                                     u16* __restrict__ out, int n4) {
  int i = blockIdx.x * 256 + threadIdx.x;
  if (i < n4) {
    float4 v = ((const float4*)in)[i];
    uint32_t w0 = (uint32_t)f2bf(v.x) | ((uint32_t)f2bf(v.y) << 16);
    uint32_t w1 = (uint32_t)f2bf(v.z) | ((uint32_t)f2bf(v.w) << 16);
    ((uint2*)out)[i] = make_uint2(w0, w1);
  }
}

// ---------------- W[K][N] fp32 -> Wt[N][K] bf16 (tiled transpose) ------------
__global__ __launch_bounds__(256) void conv_transpose_w(const float* __restrict__ W,
                                                        u16* __restrict__ Wt) {
  __shared__ float t[32][33];
  int tx = threadIdx.x & 31, ty = threadIdx.x >> 5;  // 32 x 8
  int k0 = blockIdx.x * 32, n0 = blockIdx.y * 32;
  #pragma unroll
  for (int i = 0; i < 32; i += 8)
    t[ty + i][tx] = W[(size_t)(k0 + ty + i) * Ddim + n0 + tx];
  __syncthreads();
  #pragma unroll
  for (int i = 0; i < 32; i += 8)
    Wt[(size_t)(n0 + ty + i) * Ddim + k0 + tx] = f2bf(t[tx][ty + i]);
}

// ---------------- GEMM: C[M][N] = A[M][K]bf16 @ Bt[N][K]bf16^T + bias --------
// m97-structure: 128x128 tile, BK=32, 4 waves (2x2 of 64x64), 16x16x32 MFMA,
// global_load_lds width=16, linear LDS.
template <int OUT_BF16>
__global__ __launch_bounds__(256) void gemm_bt(const u16* __restrict__ A,
                                               const u16* __restrict__ Bt,
                                               const float* __restrict__ bias,
                                               void* __restrict__ out, int M) {
  constexpr int K = 1024, N = 1024;
  __shared__ alignas(16) u16 As[BM * BK];
  __shared__ alignas(16) u16 Bs[BN * BK];
  const int tid = threadIdx.x;
  const int wid = tid >> 6, lane = tid & 63;
  const int m0 = blockIdx.x * BM, n0 = blockIdx.y * BN;
  const int wr = wid >> 1, wc = wid & 1;       // wave -> 64x64 sub-tile
  const int fr = lane & 15, fh = lane >> 4;    // fragment row/col, k-half

  f32x4 acc[4][4] = {};

  for (int k0 = 0; k0 < K; k0 += BK) {
    // stage A and Bt tiles: 128x32 bf16 each = 8KB; 2 calls x (256 lanes x 16B)
    #pragma unroll
    for (int c = 0; c < 2; ++c) {
      int e = c * 2048 + wid * 512 + lane * 8;   // element index in tile
      int r = e >> 5, col = e & 31;
      gload_lds16(A  + (size_t)(m0 + r) * K + (k0 + col), As + c * 2048 + wid * 512);
      gload_lds16(Bt + (size_t)(n0 + r) * K + (k0 + col), Bs + c * 2048 + wid * 512);
    }
    __syncthreads();   // drains vmcnt before LDS reads

    bf16x8 af[4], bfr[4];
    #pragma unroll
    for (int m = 0; m < 4; ++m)
      af[m] = *(const bf16x8*)(As + (wr * 64 + m * 16 + fr) * BK + fh * 8);
    #pragma unroll
    for (int n = 0; n < 4; ++n)
      bfr[n] = *(const bf16x8*)(Bs + (wc * 64 + n * 16 + fr) * BK + fh * 8);
    #pragma unroll
    for (int m = 0; m < 4; ++m)
      #pragma unroll
      for (int n = 0; n < 4; ++n)
        acc[m][n] = __builtin_amdgcn_mfma_f32_16x16x32_bf16(af[m], bfr[n], acc[m][n], 0, 0, 0);
    __syncthreads();
  }

  // epilogue: D[row=(lane>>4)*4+r][col=lane&15] per 16x16 fragment (m89-verified)
  #pragma unroll
  for (int n = 0; n < 4; ++n) {
    int col = n0 + wc * 64 + n * 16 + fr;
    float bv = bias[col];
    #pragma unroll
    for (int m = 0; m < 4; ++m) {
      #pragma unroll
      for (int r = 0; r < 4; ++r) {
        int row = m0 + wr * 64 + m * 16 + fh * 4 + r;
        float v = acc[m][n][r] + bv;
        if (OUT_BF16)
          ((u16*)out)[(size_t)row * N + col] = f2bf(v);
        else
          ((float*)out)[(size_t)row * N + col] = v;
      }
    }
  }
}

// ---------------- per-token attention ----------------------------------------
// One wave per token (4 tokens / 256-thread block). lane = HD row i.
// q,k,v are [64][16] per token (row-major, contiguous 1024 elems).
// S[i][k] = dot(q_i, k_k)/4 + 1e-6 ; causal mask k<=i ; softmax ; y_i = sum p*v_k
__global__ __launch_bounds__(256) void attn_tok(const u16* __restrict__ Q,
                                                const u16* __restrict__ Kb,
                                                const u16* __restrict__ Vb,
                                                u16* __restrict__ Y) {
  __shared__ float kv[4][2][HD][NH];   // 32 KB
  const int wid = threadIdx.x >> 6, lane = threadIdx.x & 63;
  const int tok = blockIdx.x * 4 + wid;
  const size_t base = (size_t)tok * Ddim;

  // load q row for this lane (16 bf16 = 32B) and stage k,v rows into LDS
  float q[NH];
  {
    const uint4* p = (const uint4*)(Q + base + lane * NH);
    uint4 a = p[0], b = p[1];
    uint32_t w[8] = {a.x, a.y, a.z, a.w, b.x, b.y, b.z, b.w};
    #pragma unroll
    for (int i = 0; i < 8; ++i) {
      q[2 * i]     = bf2f((u16)(w[i] & 0xffffu));
      q[2 * i + 1] = bf2f((u16)(w[i] >> 16));
    }
  }
  {
    const uint4* pk = (const uint4*)(Kb + base + lane * NH);
    const uint4* pv = (const uint4*)(Vb + base + lane * NH);
    uint4 ka = pk[0], kb2 = pk[1], va = pv[0], vb2 = pv[1];
    uint32_t kw[8] = {ka.x, ka.y, ka.z, ka.w, kb2.x, kb2.y, kb2.z, kb2.w};
    uint32_t vw[8] = {va.x, va.y, va.z, va.w, vb2.x, vb2.y, vb2.z, vb2.w};
    #pragma unroll
    for (int i = 0; i < 8; ++i) {
      kv[wid][0][lane][2 * i]     = bf2f((u16)(kw[i] & 0xffffu));
      kv[wid][0][lane][2 * i + 1] = bf2f((u16)(kw[i] >> 16));
      kv[wid][1][lane][2 * i]     = bf2f((u16)(vw[i] & 0xffffu));
      kv[wid][1][lane][2 * i + 1] = bf2f((u16)(vw[i] >> 16));
    }
  }
  __syncthreads();

  // scores
  float s[HD];
  #pragma unroll
  for (int k = 0; k < HD; ++k) {
    const float* kp = &kv[wid][0][k][0];
    float acc = 0.f;
    #pragma unroll
    for (int j4 = 0; j4 < 4; ++j4) {
      float4 kr = *(const float4*)(kp + 4 * j4);
      acc += q[4 * j4 + 0] * kr.x + q[4 * j4 + 1] * kr.y +
             q[4 * j4 + 2] * kr.z + q[4 * j4 + 3] * kr.w;
    }
    s[k] = acc * 0.25f + 1e-6f;
  }
  // causal softmax over k <= lane
  float mx = -3.4e38f;
  #pragma unroll
  for (int k = 0; k < HD; ++k) mx = (k <= lane) ? fmaxf(mx, s[k]) : mx;
  float sum = 0.f;
  #pragma unroll
  for (int k = 0; k < HD; ++k) {
    float e = (k <= lane) ? __expf(s[k] - mx) : 0.f;
    s[k] = e;
    sum += e;
  }
  float inv = 1.f / sum;
  // y_i = sum_k p[k] * v[k][:]
  float y[NH] = {};
  #pragma unroll
  for (int k = 0; k < HD; ++k) {
    float p = s[k];
    const float* vp = &kv[wid][1][k][0];
    #pragma unroll
    for (int j4 = 0; j4 < 4; ++j4) {
      float4 vr = *(const float4*)(vp + 4 * j4);
      y[4 * j4 + 0] += p * vr.x;
      y[4 * j4 + 1] += p * vr.y;
      y[4 * j4 + 2] += p * vr.z;
      y[4 * j4 + 3] += p * vr.w;
    }
  }
  // store y row as bf16
  uint32_t ow[8];
  #pragma unroll
  for (int i = 0; i < 8; ++i)
    ow[i] = (uint32_t)f2bf(y[2 * i] * inv) | ((uint32_t)f2bf(y[2 * i + 1] * inv) << 16);
  uint4* yp = (uint4*)(Y + base + lane * NH);
  yp[0] = make_uint4(ow[0], ow[1], ow[2], ow[3]);
  yp[1] = make_uint4(ow[4], ow[5], ow[6], ow[7]);
}

// ---------------- launch ------------------------------------------------------
extern "C" void kernel_launch(void* const* d_in, const int* in_sizes, int n_in,
                              void* d_out, int out_size, void* d_ws, size_t ws_size,
                              hipStream_t stream) {
  const float* x  = (const float*)d_in[0];
  const float* Wq = (const float*)d_in[1];
  const float* bq = (const float*)d_in[2];
  const float* Wk = (const float*)d_in[3];
  const float* bk = (const float*)d_in[4];
  const float* Wv = (const float*)d_in[5];
  const float* bv = (const float*)d_in[6];
  const float* Wo = (const float*)d_in[7];
  const float* bo = (const float*)d_in[8];
  float* out = (float*)d_out;

  // workspace layout (bf16 elements)
  u16* xb = (u16*)d_ws;                          // [16384][1024]
  u16* Wt = xb + (size_t)MTOK * Ddim;            // 4 x [1024][1024] (transposed)
  u16* Qb = Wt + 4ull * Ddim * Ddim;
  u16* Kb = Qb + (size_t)MTOK * Ddim;
  u16* Vb = Kb + (size_t)MTOK * Ddim;
  u16* Yb = xb;                                  // reuse xb after QKV GEMMs

  // 1) convert x to bf16
  conv_f32_bf16<<<(MTOK * Ddim / 4 + 255) / 256, 256, 0, stream>>>(x, xb, MTOK * Ddim / 4);

  // 2) convert+transpose weights
  dim3 tg(Ddim / 32, Ddim / 32);
  conv_transpose_w<<<tg, 256, 0, stream>>>(Wq, Wt + 0ull * Ddim * Ddim);
  conv_transpose_w<<<tg, 256, 0, stream>>>(Wk, Wt + 1ull * Ddim * Ddim);
  conv_transpose_w<<<tg, 256, 0, stream>>>(Wv, Wt + 2ull * Ddim * Ddim);
  conv_transpose_w<<<tg, 256, 0, stream>>>(Wo, Wt + 3ull * Ddim * Ddim);

  // 3) QKV projections (bf16 MFMA GEMM)
  dim3 gg(MTOK / BM, Ddim / BN);
  gemm_bt<1><<<gg, 256, 0, stream>>>(xb, Wt + 0ull * Ddim * Ddim, bq, Qb, MTOK);
  gemm_bt<1><<<gg, 256, 0, stream>>>(xb, Wt + 1ull * Ddim * Ddim, bk, Kb, MTOK);
  gemm_bt<1><<<gg, 256, 0, stream>>>(xb, Wt + 2ull * Ddim * Ddim, bv, Vb, MTOK);

  // 4) per-token attention -> Yb (bf16)
  attn_tok<<<MTOK / 4, 256, 0, stream>>>(Qb, Kb, Vb, Yb);

  // 5) output projection -> fp32 d_out
  gemm_bt<0><<<gg, 256, 0, stream>>>(Yb, Wt + 3ull * Ddim * Ddim, bo, out, MTOK);
}

// Round 2
// 330.094 us; speedup vs baseline: 1.0786x; 1.0786x over previous
//
#include <hip/hip_runtime.h>
#include <hip/hip_bf16.h>
#include <stdint.h>

typedef unsigned short u16;

#define Bdim 8
#define Ldim 2048
#define Ddim 1024
#define NH 16
#define HD 64
#define MTOK (Bdim*Ldim)   // 16384

#define BM 128
#define BN 128
#define BK 32

typedef __bf16 bf16x8 __attribute__((ext_vector_type(8)));
typedef float  f32x4  __attribute__((ext_vector_type(4)));
typedef float  f32x16 __attribute__((ext_vector_type(16)));

#define AS1 __attribute__((address_space(1)))
#define AS3 __attribute__((address_space(3)))

__device__ __forceinline__ void gload_lds16(const void* g, void* l) {
  __builtin_amdgcn_global_load_lds((const AS1 void*)g, (AS3 void*)l, 16, 0, 0);
}

__device__ __forceinline__ u16 f2bf(float f) {
  uint32_t u = __builtin_bit_cast(uint32_t, f);
  u += 0x7fffu + ((u >> 16) & 1u);   // round-to-nearest-even
  return (u16)(u >> 16);
}
__device__ __forceinline__ uint32_t pkpair(float lo, float hi) {
  return (uint32_t)f2bf(lo) | ((uint32_t)f2bf(hi) << 16);
}

// ---------------- fp32 -> bf16 convert (vectorized, 4 elems/thread) ----------
__global__ __launch_bounds__(256) void conv_f32_bf16(const float* __restrict__ in,
                                                     u16* __restrict__ out, int n4) {
  int i = blockIdx.x * 256 + threadIdx.x;
  if (i < n4) {
    float4 v = ((const float4*)in)[i];
    uint32_t w0 = (uint32_t)f2bf(v.x) | ((uint32_t)f2bf(v.y) << 16);
    uint32_t w1 = (uint32_t)f2bf(v.z) | ((uint32_t)f2bf(v.w) << 16);
    ((uint2*)out)[i] = make_uint2(w0, w1);
  }
}

// ---------------- W[K][N] fp32 -> Wt[N][K] bf16 (tiled transpose) ------------
__global__ __launch_bounds__(256) void conv_transpose_w(const float* __restrict__ W,
                                                        u16* __restrict__ Wt) {
  __shared__ float t[32][33];
  int tx = threadIdx.x & 31, ty = threadIdx.x >> 5;  // 32 x 8
  int k0 = blockIdx.x * 32, n0 = blockIdx.y * 32;
  #pragma unroll
  for (int i = 0; i < 32; i += 8)
    t[ty + i][tx] = W[(size_t)(k0 + ty + i) * Ddim + n0 + tx];
  __syncthreads();
  #pragma unroll
  for (int i = 0; i < 32; i += 8)
    Wt[(size_t)(n0 + ty + i) * Ddim + k0 + tx] = f2bf(t[tx][ty + i]);
}

// ---------------- GEMM: C[M][N] = A[M][K]bf16 @ Bt[N][K]bf16^T + bias --------
// OUT_MODE: 0 = fp32 linear, 1 = bf16 linear, 2 = bf16 with per-token V-transpose
// (store col d at (d&15)*64 + (d>>4) within the token's 1024 block).
template <int OUT_MODE>
__global__ __launch_bounds__(256) void gemm_bt(const u16* __restrict__ A,
                                               const u16* __restrict__ Bt,
                                               const float* __restrict__ bias,
                                               void* __restrict__ out, int M) {
  constexpr int K = 1024, N = 1024;
  __shared__ alignas(16) u16 As[BM * BK];
  __shared__ alignas(16) u16 Bs[BN * BK];
  const int tid = threadIdx.x;
  const int wid = tid >> 6, lane = tid & 63;
  const int m0 = blockIdx.x * BM, n0 = blockIdx.y * BN;
  const int wr = wid >> 1, wc = wid & 1;       // wave -> 64x64 sub-tile
  const int fr = lane & 15, fh = lane >> 4;    // fragment row, k-half

  f32x4 acc[4][4] = {};

  for (int k0 = 0; k0 < K; k0 += BK) {
    #pragma unroll
    for (int c = 0; c < 2; ++c) {
      int e = c * 2048 + wid * 512 + lane * 8;   // element index in tile
      int r = e >> 5, col = e & 31;
      gload_lds16(A  + (size_t)(m0 + r) * K + (k0 + col), As + c * 2048 + wid * 512);
      gload_lds16(Bt + (size_t)(n0 + r) * K + (k0 + col), Bs + c * 2048 + wid * 512);
    }
    __syncthreads();

    bf16x8 af[4], bfr[4];
    #pragma unroll
    for (int m = 0; m < 4; ++m)
      af[m] = *(const bf16x8*)(As + (wr * 64 + m * 16 + fr) * BK + fh * 8);
    #pragma unroll
    for (int n = 0; n < 4; ++n)
      bfr[n] = *(const bf16x8*)(Bs + (wc * 64 + n * 16 + fr) * BK + fh * 8);
    #pragma unroll
    for (int m = 0; m < 4; ++m)
      #pragma unroll
      for (int n = 0; n < 4; ++n)
        acc[m][n] = __builtin_amdgcn_mfma_f32_16x16x32_bf16(af[m], bfr[n], acc[m][n], 0, 0, 0);
    __syncthreads();
  }

  #pragma unroll
  for (int n = 0; n < 4; ++n) {
    int col = n0 + wc * 64 + n * 16 + fr;
    float bv = bias[col];
    #pragma unroll
    for (int m = 0; m < 4; ++m) {
      #pragma unroll
      for (int r = 0; r < 4; ++r) {
        int row = m0 + wr * 64 + m * 16 + fh * 4 + r;
        float v = acc[m][n][r] + bv;
        if (OUT_MODE == 0)
          ((float*)out)[(size_t)row * N + col] = v;
        else if (OUT_MODE == 1)
          ((u16*)out)[(size_t)row * N + col] = f2bf(v);
        else  // V: per-token transposed layout Vt[nh][hd]
          ((u16*)out)[(size_t)row * N + ((col & 15) * 64 + (col >> 4))] = f2bf(v);
      }
    }
  }
}

// ---------------- per-token attention via MFMA --------------------------------
// One wave per token. S^T = K·Q^T with mfma_f32_32x32x16_bf16 (A=K rows, B=Q rows;
// both 16B contiguous global loads). C-layout: lane holds S^T[k][i] with
// i = 32C + (lane&31), k = 32R + (r&3)+8*(r>>2)+4*(lane>>5). Tile (R=1,C=0) is
// fully masked -> 3 MFMAs. Softmax rows are lane-local + one shfl_xor(32).
// PV: Y = P·V via 6 mfma (A=P from regs, B=V from per-token-transposed Vt).
__global__ __launch_bounds__(256) void attn_mfma(const u16* __restrict__ Q,
                                                 const u16* __restrict__ Kb,
                                                 const u16* __restrict__ Vt,
                                                 u16* __restrict__ Y) {
  const int wid = threadIdx.x >> 6, lane = threadIdx.x & 63;
  const int tok = blockIdx.x * 4 + wid;
  const size_t base = (size_t)tok * Ddim;
  const int hi = lane >> 5, c31 = lane & 31;

  // QK^T fragments
  const bf16x8 kf0 = *(const bf16x8*)(Kb + base + (size_t)c31 * NH + hi * 8);
  const bf16x8 kf1 = *(const bf16x8*)(Kb + base + (size_t)(32 + c31) * NH + hi * 8);
  const bf16x8 qf0 = *(const bf16x8*)(Q  + base + (size_t)c31 * NH + hi * 8);
  const bf16x8 qf1 = *(const bf16x8*)(Q  + base + (size_t)(32 + c31) * NH + hi * 8);
  // V B-fragments from Vt[n][k] (issue early to hide latency)
  bf16x8 bv[4];
  #pragma unroll
  for (int c = 0; c < 4; ++c)
    bv[c] = *(const bf16x8*)(Vt + base + (size_t)(lane & 15) * HD + c * 16 + hi * 8);

  const f32x16 z = {};
  f32x16 s00 = __builtin_amdgcn_mfma_f32_32x32x16_bf16(kf0, qf0, z, 0, 0, 0);
  f32x16 s01 = __builtin_amdgcn_mfma_f32_32x32x16_bf16(kf0, qf1, z, 0, 0, 0);
  f32x16 s11 = __builtin_amdgcn_mfma_f32_32x32x16_bf16(kf1, qf1, z, 0, 0, 0);

  // scale + mask + softmax.  Row A: i=c31 (tile 00, cond-masked; tile 10 all-masked).
  // Row B: i=32+c31 (tile 01 all kept; tile 11 cond-masked, same condition kl<=c31).
  float a[16], b0[16], b1[16];
  float mA = -3e38f, mB = -3e38f;
  #pragma unroll
  for (int r = 0; r < 16; ++r) {
    const int kl = (r & 3) + 8 * (r >> 2) + 4 * hi;
    const bool keep = kl <= c31;
    float v00 = fmaf(s00[r], 0.25f, 1e-6f);
    float v01 = fmaf(s01[r], 0.25f, 1e-6f);
    float v11 = fmaf(s11[r], 0.25f, 1e-6f);
    a[r]  = keep ? v00 : -3e38f;
    b0[r] = v01;
    b1[r] = keep ? v11 : -3e38f;
    mA = fmaxf(mA, a[r]);
    mB = fmaxf(mB, fmaxf(b0[r], b1[r]));
  }
  mA = fmaxf(mA, __shfl_xor(mA, 32, 64));
  mB = fmaxf(mB, __shfl_xor(mB, 32, 64));
  float sA = 0.f, sB = 0.f;
  #pragma unroll
  for (int r = 0; r < 16; ++r) {
    a[r]  = __expf(a[r]  - mA);  sA += a[r];
    b0[r] = __expf(b0[r] - mB);
    b1[r] = __expf(b1[r] - mB);  sB += b0[r] + b1[r];
  }
  sA += __shfl_xor(sA, 32, 64);
  sB += __shfl_xor(sB, 32, 64);
  const float iA = __builtin_amdgcn_rcpf(sA);
  const float iB = __builtin_amdgcn_rcpf(sB);

  // pack P rows to bf16 pairs: pk[m][t] covers k_local = 8m + 4hi + {2t,2t+1}
  uint32_t pA[4][2], pB0[4][2], pB1[4][2];
  #pragma unroll
  for (int m = 0; m < 4; ++m)
    #pragma unroll
    for (int t = 0; t < 2; ++t) {
      pA [m][t] = pkpair(a [4*m+2*t] * iA, a [4*m+2*t+1] * iA);
      pB0[m][t] = pkpair(b0[4*m+2*t] * iB, b0[4*m+2*t+1] * iB);
      pB1[m][t] = pkpair(b1[4*m+2*t] * iB, b1[4*m+2*t+1] * iB);
    }

  // assemble A-fragment for K-chunk parity cp from packed P (own + lane^32 halves)
#define AFRAG(dst, src, cp) do {                                              \
    uint32_t k0_ = hi ? src[2*(cp)+1][0] : src[2*(cp)][0];                    \
    uint32_t k1_ = hi ? src[2*(cp)+1][1] : src[2*(cp)][1];                    \
    uint32_t s0_ = hi ? src[2*(cp)][0]   : src[2*(cp)+1][0];                  \
    uint32_t s1_ = hi ? src[2*(cp)][1]   : src[2*(cp)+1][1];                  \
    uint32_t r0_ = (uint32_t)__shfl_xor((int)s0_, 32, 64);                    \
    uint32_t r1_ = (uint32_t)__shfl_xor((int)s1_, 32, 64);                    \
    union { uint32_t w[4]; bf16x8 v; } u_;                                    \
    u_.w[0] = hi ? r0_ : k0_;  u_.w[1] = hi ? r1_ : k1_;                      \
    u_.w[2] = hi ? k0_ : r0_;  u_.w[3] = hi ? k1_ : r1_;                      \
    dst = u_.v;                                                               \
  } while (0)

  f32x16 y0 = {}, y1 = {};
  bf16x8 af;
  AFRAG(af, pA, 0);  y0 = __builtin_amdgcn_mfma_f32_32x32x16_bf16(af, bv[0], y0, 0, 0, 0);
  AFRAG(af, pA, 1);  y0 = __builtin_amdgcn_mfma_f32_32x32x16_bf16(af, bv[1], y0, 0, 0, 0);
  AFRAG(af, pB0, 0); y1 = __builtin_amdgcn_mfma_f32_32x32x16_bf16(af, bv[0], y1, 0, 0, 0);
  AFRAG(af, pB0, 1); y1 = __builtin_amdgcn_mfma_f32_32x32x16_bf16(af, bv[1], y1, 0, 0, 0);
  AFRAG(af, pB1, 0); y1 = __builtin_amdgcn_mfma_f32_32x32x16_bf16(af, bv[2], y1, 0, 0, 0);
  AFRAG(af, pB1, 1); y1 = __builtin_amdgcn_mfma_f32_32x32x16_bf16(af, bv[3], y1, 0, 0, 0);
#undef AFRAG

  // store Y (cols 16-31 of the MFMA tiles are duplicates; only col<16 is real)
  if (c31 < 16) {
    #pragma unroll
    for (int r = 0; r < 16; ++r) {
      const int row = (r & 3) + 8 * (r >> 2) + 4 * hi;
      Y[base + (size_t)row * NH + c31]        = f2bf(y0[r]);
      Y[base + (size_t)(32 + row) * NH + c31] = f2bf(y1[r]);
    }
  }
}

// ---------------- launch ------------------------------------------------------
extern "C" void kernel_launch(void* const* d_in, const int* in_sizes, int n_in,
                              void* d_out, int out_size, void* d_ws, size_t ws_size,
                              hipStream_t stream) {
  const float* x  = (const float*)d_in[0];
  const float* Wq = (const float*)d_in[1];
  const float* bq = (const float*)d_in[2];
  const float* Wk = (const float*)d_in[3];
  const float* bk = (const float*)d_in[4];
  const float* Wv = (const float*)d_in[5];
  const float* bv = (const float*)d_in[6];
  const float* Wo = (const float*)d_in[7];
  const float* bo = (const float*)d_in[8];
  float* out = (float*)d_out;

  u16* xb = (u16*)d_ws;                          // [16384][1024]
  u16* Wt = xb + (size_t)MTOK * Ddim;            // 4 x [1024][1024] (transposed)
  u16* Qb = Wt + 4ull * Ddim * Ddim;
  u16* Kb = Qb + (size_t)MTOK * Ddim;
  u16* Vb = Kb + (size_t)MTOK * Ddim;            // holds Vt (per-token [nh][hd])
  u16* Yb = xb;                                  // reuse xb after QKV GEMMs

  conv_f32_bf16<<<(MTOK * Ddim / 4 + 255) / 256, 256, 0, stream>>>(x, xb, MTOK * Ddim / 4);

  dim3 tg(Ddim / 32, Ddim / 32);
  conv_transpose_w<<<tg, 256, 0, stream>>>(Wq, Wt + 0ull * Ddim * Ddim);
  conv_transpose_w<<<tg, 256, 0, stream>>>(Wk, Wt + 1ull * Ddim * Ddim);
  conv_transpose_w<<<tg, 256, 0, stream>>>(Wv, Wt + 2ull * Ddim * Ddim);
  conv_transpose_w<<<tg, 256, 0, stream>>>(Wo, Wt + 3ull * Ddim * Ddim);

  dim3 gg(MTOK / BM, Ddim / BN);
  gemm_bt<1><<<gg, 256, 0, stream>>>(xb, Wt + 0ull * Ddim * Ddim, bq, Qb, MTOK);
  gemm_bt<1><<<gg, 256, 0, stream>>>(xb, Wt + 1ull * Ddim * Ddim, bk, Kb, MTOK);
  gemm_bt<2><<<gg, 256, 0, stream>>>(xb, Wt + 2ull * Ddim * Ddim, bv, Vb, MTOK);

  attn_mfma<<<MTOK / 4, 256, 0, stream>>>(Qb, Kb, Vb, Yb);

  gemm_bt<0><<<gg, 256, 0, stream>>>(Yb, Wt + 3ull * Ddim * Ddim, bo, out, MTOK);
}

// Round 3
// 244.388 us; speedup vs baseline: 1.4568x; 1.3507x over previous
//
#include <hip/hip_runtime.h>
#include <hip/hip_bf16.h>
#include <stdint.h>

typedef unsigned short u16;

#define Bdim 8
#define Ldim 2048
#define Ddim 1024
#define NH 16
#define HD 64
#define MTOK (Bdim*Ldim)   // 16384

#define BM 128
#define BN 128
#define BK 32

typedef __bf16 bf16x8 __attribute__((ext_vector_type(8)));
typedef float  f32x4  __attribute__((ext_vector_type(4)));
typedef float  f32x16 __attribute__((ext_vector_type(16)));

#define AS1 __attribute__((address_space(1)))
#define AS3 __attribute__((address_space(3)))

__device__ __forceinline__ void gload_lds16(const void* g, void* l) {
  __builtin_amdgcn_global_load_lds((const AS1 void*)g, (AS3 void*)l, 16, 0, 0);
}

__device__ __forceinline__ u16 f2bf(float f) {
  uint32_t u = __builtin_bit_cast(uint32_t, f);
  u += 0x7fffu + ((u >> 16) & 1u);   // round-to-nearest-even
  return (u16)(u >> 16);
}
__device__ __forceinline__ uint32_t pkpair(float lo, float hi) {
  return (uint32_t)f2bf(lo) | ((uint32_t)f2bf(hi) << 16);
}

// ---------------- fp32 -> bf16 convert (vectorized, 4 elems/thread) ----------
__global__ __launch_bounds__(256) void conv_f32_bf16(const float* __restrict__ in,
                                                     u16* __restrict__ out, int n4) {
  int i = blockIdx.x * 256 + threadIdx.x;
  if (i < n4) {
    float4 v = ((const float4*)in)[i];
    uint32_t w0 = (uint32_t)f2bf(v.x) | ((uint32_t)f2bf(v.y) << 16);
    uint32_t w1 = (uint32_t)f2bf(v.z) | ((uint32_t)f2bf(v.w) << 16);
    ((uint2*)out)[i] = make_uint2(w0, w1);
  }
}

// ---------------- W[K][N] fp32 -> Wt[N][K] bf16 (tiled transpose) ------------
__global__ __launch_bounds__(256) void conv_transpose_w(const float* __restrict__ W,
                                                        u16* __restrict__ Wt) {
  __shared__ float t[32][33];
  int tx = threadIdx.x & 31, ty = threadIdx.x >> 5;  // 32 x 8
  int k0 = blockIdx.x * 32, n0 = blockIdx.y * 32;
  #pragma unroll
  for (int i = 0; i < 32; i += 8)
    t[ty + i][tx] = W[(size_t)(k0 + ty + i) * Ddim + n0 + tx];
  __syncthreads();
  #pragma unroll
  for (int i = 0; i < 32; i += 8)
    Wt[(size_t)(n0 + ty + i) * Ddim + k0 + tx] = f2bf(t[tx][ty + i]);
}

// ---------------- GEMM: C[M][N] = A[M][K]bf16 @ Bt[N][K]bf16^T + bias --------
// m97-structure loop (verified). FUSED=1: N=3072 (Q|K|V outputs, bf16; V in
// per-token transposed layout). FUSED=0: N=1024, fp32 output.
// Coalesced epilogue through LDS (kills the 6x HBM write amplification).
// XCD-bijective swizzle: each XCD owns a contiguous 16-Mtile chunk.
template <int FUSED>
__global__ __launch_bounds__(256) void gemm_bt(const u16* __restrict__ A,
                                               const u16* __restrict__ Bt,
                                               const float* __restrict__ b0p,
                                               const float* __restrict__ b1p,
                                               const float* __restrict__ b2p,
                                               void* __restrict__ o0,
                                               void* __restrict__ o1,
                                               void* __restrict__ o2) {
  constexpr int K = 1024;
  __shared__ alignas(16) unsigned char pool[34816];
  u16* As = (u16*)pool;          // [128][32] bf16
  u16* Bs = As + 4096;           // [128][32] bf16
  const int tid = threadIdx.x;
  const int wid = tid >> 6, lane = tid & 63;
  // XCD swizzle: bid%8 = XCD; within XCD walk 16 m-tiles fast (A-chunk 4MB L2-resident)
  const int bid = blockIdx.x;
  const int xcd = bid & 7, idx = bid >> 3;
  const int mt = (xcd << 4) | (idx & 15);
  const int nt = idx >> 4;                 // FUSED: [0,24)  else [0,8)
  const int m0 = mt * BM;
  const int n0g = nt * BN;                 // row offset into Bt
  const int wr = wid >> 1, wc = wid & 1;
  const int fr = lane & 15, fh = lane >> 4;

  f32x4 acc[4][4] = {};

  for (int k0 = 0; k0 < K; k0 += BK) {
    #pragma unroll
    for (int c = 0; c < 2; ++c) {
      int e = c * 2048 + wid * 512 + lane * 8;
      int r = e >> 5, col = e & 31;
      gload_lds16(A  + (size_t)(m0  + r) * K + (k0 + col), As + c * 2048 + wid * 512);
      gload_lds16(Bt + (size_t)(n0g + r) * K + (k0 + col), Bs + c * 2048 + wid * 512);
    }
    __syncthreads();

    bf16x8 af[4], bfr[4];
    #pragma unroll
    for (int m = 0; m < 4; ++m)
      af[m] = *(const bf16x8*)(As + (wr * 64 + m * 16 + fr) * BK + fh * 8);
    #pragma unroll
    for (int n = 0; n < 4; ++n)
      bfr[n] = *(const bf16x8*)(Bs + (wc * 64 + n * 16 + fr) * BK + fh * 8);
    #pragma unroll
    for (int m = 0; m < 4; ++m)
      #pragma unroll
      for (int n = 0; n < 4; ++n)
        acc[m][n] = __builtin_amdgcn_mfma_f32_16x16x32_bf16(af[m], bfr[n], acc[m][n], 0, 0, 0);
    __syncthreads();
  }

  if (FUSED) {
    // which output (Q/K/V) and local N offset
    const int which = nt >> 3;
    const int n0l = (nt & 7) * BN;
    const float* bias = which == 0 ? b0p : which == 1 ? b1p : b2p;
    u16* Out = (u16*)(which == 0 ? o0 : which == 1 ? o1 : o2);

    u16* Ct = (u16*)pool;   // [128][136] (pad breaks bank aliasing)
    #pragma unroll
    for (int n = 0; n < 4; ++n) {
      int col = wc * 64 + n * 16 + fr;
      float bvv = bias[n0l + col];
      #pragma unroll
      for (int m = 0; m < 4; ++m)
        #pragma unroll
        for (int r = 0; r < 4; ++r) {
          int row = wr * 64 + m * 16 + fh * 4 + r;
          Ct[row * 136 + col] = f2bf(acc[m][n][r] + bvv);
        }
    }
    __syncthreads();
    if (which != 2) {
      // linear bf16 rows: 16B/lane fully coalesced
      #pragma unroll
      for (int it = 0; it < 8; ++it) {
        int q = it * 256 + tid, r = q >> 4, cc = q & 15;
        uint4 v = *(const uint4*)(Ct + r * 136 + cc * 8);
        *(uint4*)(Out + (size_t)(m0 + r) * Ddim + n0l + cc * 8) = v;
      }
    } else {
      // V: per-token transposed Vt[i=d&15][k=d>>4]; 8 gathered u16 -> one 16B store
      #pragma unroll
      for (int it = 0; it < 8; ++it) {
        int q = it * 256 + tid, r = q >> 4, i = q & 15;
        u16 tmp[8];
        #pragma unroll
        for (int j = 0; j < 8; ++j) tmp[j] = Ct[r * 136 + i + 16 * j];
        *(uint4*)(Out + (size_t)(m0 + r) * Ddim + i * 64 + (n0l >> 4)) = *(uint4*)tmp;
      }
    }
  } else {
    // fp32 output, two 64-col half-passes through LDS
    float* Cf = (float*)pool;  // [128][68]
    float* Out = (float*)o0;
    #pragma unroll
    for (int h = 0; h < 2; ++h) {
      if (wc == h) {
        #pragma unroll
        for (int n = 0; n < 4; ++n) {
          int col = n * 16 + fr;
          float bvv = b0p[n0g + h * 64 + col];
          #pragma unroll
          for (int m = 0; m < 4; ++m)
            #pragma unroll
            for (int r = 0; r < 4; ++r) {
              int row = wr * 64 + m * 16 + fh * 4 + r;
              Cf[row * 68 + col] = acc[m][n][r] + bvv;
            }
        }
      }
      __syncthreads();
      #pragma unroll
      for (int it = 0; it < 8; ++it) {
        int q = it * 256 + tid, r = q >> 4, cc = q & 15;
        float4 v = *(const float4*)(Cf + r * 68 + cc * 4);
        *(float4*)(Out + (size_t)(m0 + r) * Ddim + n0g + h * 64 + cc * 4) = v;
      }
      __syncthreads();
    }
  }
}

// ---------------- per-token attention via MFMA --------------------------------
// One wave per token. S^T = K·Q^T with mfma_f32_32x32x16_bf16; softmax rows are
// lane-local + one shfl_xor(32). PV: Y = P·V via 6 mfma (V from per-token Vt).
__global__ __launch_bounds__(256) void attn_mfma(const u16* __restrict__ Q,
                                                 const u16* __restrict__ Kb,
                                                 const u16* __restrict__ Vt,
                                                 u16* __restrict__ Y) {
  const int wid = threadIdx.x >> 6, lane = threadIdx.x & 63;
  const int tok = blockIdx.x * 4 + wid;
  const size_t base = (size_t)tok * Ddim;
  const int hi = lane >> 5, c31 = lane & 31;

  const bf16x8 kf0 = *(const bf16x8*)(Kb + base + (size_t)c31 * NH + hi * 8);
  const bf16x8 kf1 = *(const bf16x8*)(Kb + base + (size_t)(32 + c31) * NH + hi * 8);
  const bf16x8 qf0 = *(const bf16x8*)(Q  + base + (size_t)c31 * NH + hi * 8);
  const bf16x8 qf1 = *(const bf16x8*)(Q  + base + (size_t)(32 + c31) * NH + hi * 8);
  bf16x8 bv[4];
  #pragma unroll
  for (int c = 0; c < 4; ++c)
    bv[c] = *(const bf16x8*)(Vt + base + (size_t)(lane & 15) * HD + c * 16 + hi * 8);

  const f32x16 z = {};
  f32x16 s00 = __builtin_amdgcn_mfma_f32_32x32x16_bf16(kf0, qf0, z, 0, 0, 0);
  f32x16 s01 = __builtin_amdgcn_mfma_f32_32x32x16_bf16(kf0, qf1, z, 0, 0, 0);
  f32x16 s11 = __builtin_amdgcn_mfma_f32_32x32x16_bf16(kf1, qf1, z, 0, 0, 0);

  float a[16], b0[16], b1[16];
  float mA = -3e38f, mB = -3e38f;
  #pragma unroll
  for (int r = 0; r < 16; ++r) {
    const int kl = (r & 3) + 8 * (r >> 2) + 4 * hi;
    const bool keep = kl <= c31;
    float v00 = fmaf(s00[r], 0.25f, 1e-6f);
    float v01 = fmaf(s01[r], 0.25f, 1e-6f);
    float v11 = fmaf(s11[r], 0.25f, 1e-6f);
    a[r]  = keep ? v00 : -3e38f;
    b0[r] = v01;
    b1[r] = keep ? v11 : -3e38f;
    mA = fmaxf(mA, a[r]);
    mB = fmaxf(mB, fmaxf(b0[r], b1[r]));
  }
  mA = fmaxf(mA, __shfl_xor(mA, 32, 64));
  mB = fmaxf(mB, __shfl_xor(mB, 32, 64));
  float sA = 0.f, sB = 0.f;
  #pragma unroll
  for (int r = 0; r < 16; ++r) {
    a[r]  = __expf(a[r]  - mA);  sA += a[r];
    b0[r] = __expf(b0[r] - mB);
    b1[r] = __expf(b1[r] - mB);  sB += b0[r] + b1[r];
  }
  sA += __shfl_xor(sA, 32, 64);
  sB += __shfl_xor(sB, 32, 64);
  const float iA = __builtin_amdgcn_rcpf(sA);
  const float iB = __builtin_amdgcn_rcpf(sB);

  uint32_t pA[4][2], pB0[4][2], pB1[4][2];
  #pragma unroll
  for (int m = 0; m < 4; ++m)
    #pragma unroll
    for (int t = 0; t < 2; ++t) {
      pA [m][t] = pkpair(a [4*m+2*t] * iA, a [4*m+2*t+1] * iA);
      pB0[m][t] = pkpair(b0[4*m+2*t] * iB, b0[4*m+2*t+1] * iB);
      pB1[m][t] = pkpair(b1[4*m+2*t] * iB, b1[4*m+2*t+1] * iB);
    }

#define AFRAG(dst, src, cp) do {                                              \
    uint32_t k0_ = hi ? src[2*(cp)+1][0] : src[2*(cp)][0];                    \
    uint32_t k1_ = hi ? src[2*(cp)+1][1] : src[2*(cp)][1];                    \
    uint32_t s0_ = hi ? src[2*(cp)][0]   : src[2*(cp)+1][0];                  \
    uint32_t s1_ = hi ? src[2*(cp)][1]   : src[2*(cp)+1][1];                  \
    uint32_t r0_ = (uint32_t)__shfl_xor((int)s0_, 32, 64);                    \
    uint32_t r1_ = (uint32_t)__shfl_xor((int)s1_, 32, 64);                    \
    union { uint32_t w[4]; bf16x8 v; } u_;                                    \
    u_.w[0] = hi ? r0_ : k0_;  u_.w[1] = hi ? r1_ : k1_;                      \
    u_.w[2] = hi ? k0_ : r0_;  u_.w[3] = hi ? k1_ : r1_;                      \
    dst = u_.v;                                                               \
  } while (0)

  f32x16 y0 = {}, y1 = {};
  bf16x8 af;
  AFRAG(af, pA, 0);  y0 = __builtin_amdgcn_mfma_f32_32x32x16_bf16(af, bv[0], y0, 0, 0, 0);
  AFRAG(af, pA, 1);  y0 = __builtin_amdgcn_mfma_f32_32x32x16_bf16(af, bv[1], y0, 0, 0, 0);
  AFRAG(af, pB0, 0); y1 = __builtin_amdgcn_mfma_f32_32x32x16_bf16(af, bv[0], y1, 0, 0, 0);
  AFRAG(af, pB0, 1); y1 = __builtin_amdgcn_mfma_f32_32x32x16_bf16(af, bv[1], y1, 0, 0, 0);
  AFRAG(af, pB1, 0); y1 = __builtin_amdgcn_mfma_f32_32x32x16_bf16(af, bv[2], y1, 0, 0, 0);
  AFRAG(af, pB1, 1); y1 = __builtin_amdgcn_mfma_f32_32x32x16_bf16(af, bv[3], y1, 0, 0, 0);
#undef AFRAG

  if (c31 < 16) {
    #pragma unroll
    for (int r = 0; r < 16; ++r) {
      const int row = (r & 3) + 8 * (r >> 2) + 4 * hi;
      Y[base + (size_t)row * NH + c31]        = f2bf(y0[r]);
      Y[base + (size_t)(32 + row) * NH + c31] = f2bf(y1[r]);
    }
  }
}

// ---------------- launch ------------------------------------------------------
extern "C" void kernel_launch(void* const* d_in, const int* in_sizes, int n_in,
                              void* d_out, int out_size, void* d_ws, size_t ws_size,
                              hipStream_t stream) {
  const float* x  = (const float*)d_in[0];
  const float* Wq = (const float*)d_in[1];
  const float* bq = (const float*)d_in[2];
  const float* Wk = (const float*)d_in[3];
  const float* bk = (const float*)d_in[4];
  const float* Wv = (const float*)d_in[5];
  const float* bv = (const float*)d_in[6];
  const float* Wo = (const float*)d_in[7];
  const float* bo = (const float*)d_in[8];
  float* out = (float*)d_out;

  u16* xb = (u16*)d_ws;                          // [16384][1024]
  u16* Wt = xb + (size_t)MTOK * Ddim;            // 4 x [1024][1024] (transposed; q,k,v contiguous)
  u16* Qb = Wt + 4ull * Ddim * Ddim;
  u16* Kb = Qb + (size_t)MTOK * Ddim;
  u16* Vb = Kb + (size_t)MTOK * Ddim;            // Vt (per-token [nh][hd])
  u16* Yb = xb;                                  // reuse xb after attention input consumed

  conv_f32_bf16<<<(MTOK * Ddim / 4 + 255) / 256, 256, 0, stream>>>(x, xb, MTOK * Ddim / 4);

  dim3 tg(Ddim / 32, Ddim / 32);
  conv_transpose_w<<<tg, 256, 0, stream>>>(Wq, Wt + 0ull * Ddim * Ddim);
  conv_transpose_w<<<tg, 256, 0, stream>>>(Wk, Wt + 1ull * Ddim * Ddim);
  conv_transpose_w<<<tg, 256, 0, stream>>>(Wv, Wt + 2ull * Ddim * Ddim);
  conv_transpose_w<<<tg, 256, 0, stream>>>(Wo, Wt + 3ull * Ddim * Ddim);

  // fused QKV GEMM: Bt = [Wq^T | Wk^T | Wv^T] as 3072 rows
  gemm_bt<1><<<dim3(3072), 256, 0, stream>>>(xb, Wt, bq, bk, bv, Qb, Kb, Vb);

  attn_mfma<<<MTOK / 4, 256, 0, stream>>>(Qb, Kb, Vb, Yb);

  gemm_bt<0><<<dim3(1024), 256, 0, stream>>>(Yb, Wt + 3ull * Ddim * Ddim,
                                             bo, bo, bo, out, out, out);
}

// Round 4
// 213.349 us; speedup vs baseline: 1.6687x; 1.1455x over previous
//
#include <hip/hip_runtime.h>
#include <hip/hip_bf16.h>
#include <stdint.h>

typedef unsigned short u16;

#define Bdim 8
#define Ldim 2048
#define Ddim 1024
#define NH 16
#define HD 64
#define MTOK (Bdim*Ldim)   // 16384

typedef __bf16 bf16x8 __attribute__((ext_vector_type(8)));
typedef float  f32x4  __attribute__((ext_vector_type(4)));
typedef float  f32x16 __attribute__((ext_vector_type(16)));

#define AS1 __attribute__((address_space(1)))
#define AS3 __attribute__((address_space(3)))

__device__ __forceinline__ void gload_lds16(const void* g, void* l) {
  __builtin_amdgcn_global_load_lds((const AS1 void*)g, (AS3 void*)l, 16, 0, 0);
}

__device__ __forceinline__ u16 f2bf(float f) {
  uint32_t u = __builtin_bit_cast(uint32_t, f);
  u += 0x7fffu + ((u >> 16) & 1u);   // round-to-nearest-even
  return (u16)(u >> 16);
}
__device__ __forceinline__ uint32_t pkpair(float lo, float hi) {
  return (uint32_t)f2bf(lo) | ((uint32_t)f2bf(hi) << 16);
}

// ---------------- fp32 -> bf16 convert ---------------------------------------
__global__ __launch_bounds__(256) void conv_f32_bf16(const float* __restrict__ in,
                                                     u16* __restrict__ out, int n4) {
  int i = blockIdx.x * 256 + threadIdx.x;
  if (i < n4) {
    float4 v = ((const float4*)in)[i];
    uint32_t w0 = (uint32_t)f2bf(v.x) | ((uint32_t)f2bf(v.y) << 16);
    uint32_t w1 = (uint32_t)f2bf(v.z) | ((uint32_t)f2bf(v.w) << 16);
    ((uint2*)out)[i] = make_uint2(w0, w1);
  }
}

// ---------------- W[K][N] fp32 -> Wt[N][K] bf16 (tiled transpose) ------------
__global__ __launch_bounds__(256) void conv_transpose_w(const float* __restrict__ W,
                                                        u16* __restrict__ Wt) {
  __shared__ float t[32][33];
  int tx = threadIdx.x & 31, ty = threadIdx.x >> 5;
  int k0 = blockIdx.x * 32, n0 = blockIdx.y * 32;
  #pragma unroll
  for (int i = 0; i < 32; i += 8)
    t[ty + i][tx] = W[(size_t)(k0 + ty + i) * Ddim + n0 + tx];
  __syncthreads();
  #pragma unroll
  for (int i = 0; i < 32; i += 8)
    Wt[(size_t)(n0 + ty + i) * Ddim + k0 + tx] = f2bf(t[tx][ty + i]);
}

// ---------------- 256x256 deep-pipelined GEMM (T2+T3+T4+T5) ------------------
// C[M][N] = A[M][1024] @ Bt[N][1024]^T + bias. 512 threads = 8 waves (2Mx4N),
// per-wave 128x64 output (acc[8][4]). BK=64, 2 K-tiles double-buffered (128KB).
// Staging: global_load_lds x16B, global source pre-swizzled (col16 ^= row&7),
// ds_read applies same XOR -> conflict-free. Counted vmcnt(8) per iteration,
// raw s_barrier (no implicit vmcnt(0) drain). setprio around MFMA cluster.
// FUSED=1: N=3072 (Q|K|V bf16; V per-token transposed). FUSED=0: N=1024 fp32.
template <int FUSED>
__global__ __launch_bounds__(512, 2) void gemm256(const u16* __restrict__ A,
                                                  const u16* __restrict__ Bt,
                                                  const float* __restrict__ b0p,
                                                  const float* __restrict__ b1p,
                                                  const float* __restrict__ b2p,
                                                  void* __restrict__ o0,
                                                  void* __restrict__ o1,
                                                  void* __restrict__ o2) {
  __shared__ alignas(16) u16 LP[65536];          // 128 KB: A[2][256][64] | B[2][256][64]
  u16* LA = LP;                                   // + buf*16384
  u16* LB = LP + 32768;

  const int tid = threadIdx.x;
  const int wid = tid >> 6, lane = tid & 63;
  const int wr = wid >> 2, wc = wid & 3;          // 2x4 wave grid
  const int fr = lane & 15, fh = lane >> 4;       // fragment row, k-quarter
  const int key = fr & 7;                          // ds_read swizzle key

  // XCD-aware tile mapping: mt-fast within XCD (A-chunk 4MB L2-resident)
  const int bid = blockIdx.x;
  const int xcd = bid & 7, idx = bid >> 3;
  const int mt = xcd * 8 + (idx & 7);
  const int nt = idx >> 3;                         // FUSED: [0,12) else [0,4)
  const int m0 = mt * 256;
  const int n0g = nt * 256;

  // staging source pointers (pre-swizzled global column): lane covers
  // LDS row (wid*8 + lane>>3) col16 (lane&7); loads logical col16^(row&7)
  const int srow = wid * 8 + (lane >> 3);
  const int scol = ((lane & 7) ^ (lane >> 3)) * 8;
  const u16* aG = A  + (size_t)(m0  + srow) * 1024 + scol;
  const u16* bG = Bt + (size_t)(n0g + srow) * 1024 + scol;
  const int ldsW = wid * 512;                      // u16, wave-uniform

#define STAGE(tile, buf) do {                                                  \
    const u16* ag_ = aG + (size_t)(tile) * 64;                                  \
    const u16* bg_ = bG + (size_t)(tile) * 64;                                  \
    _Pragma("unroll")                                                           \
    for (int s_ = 0; s_ < 4; ++s_) {                                            \
      gload_lds16(ag_ + (size_t)s_ * 65536, LA + (buf) * 16384 + s_ * 4096 + ldsW); \
      gload_lds16(bg_ + (size_t)s_ * 65536, LB + (buf) * 16384 + s_ * 4096 + ldsW); \
    }                                                                           \
  } while (0)

  f32x4 acc[8][4] = {};

#define COMPUTE(buf) do {                                                       \
    _Pragma("unroll")                                                           \
    for (int ks_ = 0; ks_ < 2; ++ks_) {                                         \
      bf16x8 af_[8], bf_[4];                                                    \
      const int p_ = ((ks_ * 4 + fh) ^ key) * 8;                                \
      _Pragma("unroll")                                                         \
      for (int m_ = 0; m_ < 8; ++m_)                                            \
        af_[m_] = *(const bf16x8*)(LA + (buf) * 16384 +                         \
                                   (wr * 128 + m_ * 16 + fr) * 64 + p_);        \
      _Pragma("unroll")                                                         \
      for (int n_ = 0; n_ < 4; ++n_)                                            \
        bf_[n_] = *(const bf16x8*)(LB + (buf) * 16384 +                         \
                                   (wc * 64 + n_ * 16 + fr) * 64 + p_);         \
      __builtin_amdgcn_s_setprio(1);                                            \
      _Pragma("unroll")                                                         \
      for (int m_ = 0; m_ < 8; ++m_)                                            \
        _Pragma("unroll")                                                       \
        for (int n_ = 0; n_ < 4; ++n_)                                          \
          acc[m_][n_] = __builtin_amdgcn_mfma_f32_16x16x32_bf16(                \
              af_[m_], bf_[n_], acc[m_][n_], 0, 0, 0);                          \
      __builtin_amdgcn_s_setprio(0);                                            \
    }                                                                           \
  } while (0)

  STAGE(0, 0);                                    // prologue: tile 0 -> buf 0
  #pragma unroll 1
  for (int t = 0; t < 15; ++t) {
    const int cur = t & 1;
    STAGE(t + 1, cur ^ 1);                        // prefetch into dead buffer
    asm volatile("s_waitcnt vmcnt(8)" ::: "memory");   // tile t complete; t+1 in flight
    __builtin_amdgcn_s_barrier();
    COMPUTE(cur);
    asm volatile("s_waitcnt lgkmcnt(0)" ::: "memory"); // all LDS reads landed
    __builtin_amdgcn_s_barrier();                 // buf cur now dead
  }
  asm volatile("s_waitcnt vmcnt(0)" ::: "memory");     // epilogue drain (legal)
  __builtin_amdgcn_s_barrier();
  COMPUTE(1);
  __syncthreads();                                // LDS reuse below

  if (FUSED) {
    const int which = nt >> 2;                    // 0 Q, 1 K, 2 V
    const int n0l = (nt & 3) * 256;
    const float* bias = which == 0 ? b0p : which == 1 ? b1p : b2p;
    u16* Out = (u16*)(which == 0 ? o0 : which == 1 ? o1 : o2);
    u16* Ct = LP;                                 // [4 regions][128][72] u16
    #pragma unroll 1
    for (int h = 0; h < 2; ++h) {
      if (h) __syncthreads();
      if (wr == h) {
        #pragma unroll
        for (int n = 0; n < 4; ++n) {
          float bvv = bias[n0l + wc * 64 + n * 16 + fr];
          #pragma unroll
          for (int m = 0; m < 8; ++m)
            #pragma unroll
            for (int r = 0; r < 4; ++r)
              Ct[wc * 9216 + (m * 16 + fh * 4 + r) * 72 + n * 16 + fr] =
                  f2bf(acc[m][n][r] + bvv);
        }
      }
      __syncthreads();
      if (which != 2) {
        #pragma unroll
        for (int j = 0; j < 8; ++j) {
          int r = j * 16 + (tid >> 5), c8 = tid & 31;
          uint4 v = *(const uint4*)(Ct + (c8 >> 3) * 9216 + r * 72 + (c8 & 7) * 8);
          *(uint4*)(Out + (size_t)(m0 + h * 128 + r) * Ddim + n0l + c8 * 8) = v;
        }
      } else {
        // V per-token transposed: Vt[i=d&15][k=d>>4]; 32B chunks per (row,i)
        #pragma unroll
        for (int j = 0; j < 4; ++j) {
          int q = j * 512 + tid, r = q >> 4, i = q & 15;
          u16 tmp[16];
          #pragma unroll
          for (int jj = 0; jj < 16; ++jj) {
            int c = i + 16 * jj;
            tmp[jj] = Ct[(c >> 6) * 9216 + r * 72 + (c & 63)];
          }
          u16* dst = Out + (size_t)(m0 + h * 128 + r) * Ddim + i * 64 + (n0l >> 4);
          *(uint4*)dst = *(uint4*)tmp;
          *(uint4*)(dst + 8) = *(uint4*)(tmp + 8);
        }
      }
      __syncthreads();
    }
  } else {
    float* Cf = (float*)LP;                       // [2 regions][128][68] f32
    float* Out = (float*)o0;
    #pragma unroll 1
    for (int h = 0; h < 4; ++h) {                 // (mh = h>>1, nh = h&1)
      if (h) __syncthreads();
      if (wr == (h >> 1) && (wc >> 1) == (h & 1)) {
        #pragma unroll
        for (int n = 0; n < 4; ++n) {
          int col = (wc & 1) * 64 + n * 16 + fr;
          float bvv = b0p[n0g + (h & 1) * 128 + col];
          #pragma unroll
          for (int m = 0; m < 8; ++m)
            #pragma unroll
            for (int r = 0; r < 4; ++r)
              Cf[(wc & 1) * 8704 + (m * 16 + fh * 4 + r) * 68 + n * 16 + fr] =
                  acc[m][n][r] + bvv;
        }
      }
      __syncthreads();
      #pragma unroll
      for (int j = 0; j < 8; ++j) {
        int r = j * 16 + (tid >> 5), c4 = tid & 31;
        float4 v = *(const float4*)(Cf + (c4 >> 4) * 8704 + r * 68 + (c4 & 15) * 4);
        *(float4*)(Out + (size_t)(m0 + (h >> 1) * 128 + r) * Ddim +
                   n0g + (h & 1) * 128 + c4 * 4) = v;
      }
      __syncthreads();
    }
  }
#undef STAGE
#undef COMPUTE
}

// ---------------- per-token attention via MFMA (unchanged, verified) ---------
__global__ __launch_bounds__(256) void attn_mfma(const u16* __restrict__ Q,
                                                 const u16* __restrict__ Kb,
                                                 const u16* __restrict__ Vt,
                                                 u16* __restrict__ Y) {
  const int wid = threadIdx.x >> 6, lane = threadIdx.x & 63;
  const int tok = blockIdx.x * 4 + wid;
  const size_t base = (size_t)tok * Ddim;
  const int hi = lane >> 5, c31 = lane & 31;

  const bf16x8 kf0 = *(const bf16x8*)(Kb + base + (size_t)c31 * NH + hi * 8);
  const bf16x8 kf1 = *(const bf16x8*)(Kb + base + (size_t)(32 + c31) * NH + hi * 8);
  const bf16x8 qf0 = *(const bf16x8*)(Q  + base + (size_t)c31 * NH + hi * 8);
  const bf16x8 qf1 = *(const bf16x8*)(Q  + base + (size_t)(32 + c31) * NH + hi * 8);
  bf16x8 bv[4];
  #pragma unroll
  for (int c = 0; c < 4; ++c)
    bv[c] = *(const bf16x8*)(Vt + base + (size_t)(lane & 15) * HD + c * 16 + hi * 8);

  const f32x16 z = {};
  f32x16 s00 = __builtin_amdgcn_mfma_f32_32x32x16_bf16(kf0, qf0, z, 0, 0, 0);
  f32x16 s01 = __builtin_amdgcn_mfma_f32_32x32x16_bf16(kf0, qf1, z, 0, 0, 0);
  f32x16 s11 = __builtin_amdgcn_mfma_f32_32x32x16_bf16(kf1, qf1, z, 0, 0, 0);

  float a[16], b0[16], b1[16];
  float mA = -3e38f, mB = -3e38f;
  #pragma unroll
  for (int r = 0; r < 16; ++r) {
    const int kl = (r & 3) + 8 * (r >> 2) + 4 * hi;
    const bool keep = kl <= c31;
    float v00 = fmaf(s00[r], 0.25f, 1e-6f);
    float v01 = fmaf(s01[r], 0.25f, 1e-6f);
    float v11 = fmaf(s11[r], 0.25f, 1e-6f);
    a[r]  = keep ? v00 : -3e38f;
    b0[r] = v01;
    b1[r] = keep ? v11 : -3e38f;
    mA = fmaxf(mA, a[r]);
    mB = fmaxf(mB, fmaxf(b0[r], b1[r]));
  }
  mA = fmaxf(mA, __shfl_xor(mA, 32, 64));
  mB = fmaxf(mB, __shfl_xor(mB, 32, 64));
  float sA = 0.f, sB = 0.f;
  #pragma unroll
  for (int r = 0; r < 16; ++r) {
    a[r]  = __expf(a[r]  - mA);  sA += a[r];
    b0[r] = __expf(b0[r] - mB);
    b1[r] = __expf(b1[r] - mB);  sB += b0[r] + b1[r];
  }
  sA += __shfl_xor(sA, 32, 64);
  sB += __shfl_xor(sB, 32, 64);
  const float iA = __builtin_amdgcn_rcpf(sA);
  const float iB = __builtin_amdgcn_rcpf(sB);

  uint32_t pA[4][2], pB0[4][2], pB1[4][2];
  #pragma unroll
  for (int m = 0; m < 4; ++m)
    #pragma unroll
    for (int t = 0; t < 2; ++t) {
      pA [m][t] = pkpair(a [4*m+2*t] * iA, a [4*m+2*t+1] * iA);
      pB0[m][t] = pkpair(b0[4*m+2*t] * iB, b0[4*m+2*t+1] * iB);
      pB1[m][t] = pkpair(b1[4*m+2*t] * iB, b1[4*m+2*t+1] * iB);
    }

#define AFRAG(dst, src, cp) do {                                              \
    uint32_t k0_ = hi ? src[2*(cp)+1][0] : src[2*(cp)][0];                    \
    uint32_t k1_ = hi ? src[2*(cp)+1][1] : src[2*(cp)][1];                    \
    uint32_t s0_ = hi ? src[2*(cp)][0]   : src[2*(cp)+1][0];                  \
    uint32_t s1_ = hi ? src[2*(cp)][1]   : src[2*(cp)+1][1];                  \
    uint32_t r0_ = (uint32_t)__shfl_xor((int)s0_, 32, 64);                    \
    uint32_t r1_ = (uint32_t)__shfl_xor((int)s1_, 32, 64);                    \
    union { uint32_t w[4]; bf16x8 v; } u_;                                    \
    u_.w[0] = hi ? r0_ : k0_;  u_.w[1] = hi ? r1_ : k1_;                      \
    u_.w[2] = hi ? k0_ : r0_;  u_.w[3] = hi ? k1_ : r1_;                      \
    dst = u_.v;                                                               \
  } while (0)

  f32x16 y0 = {}, y1 = {};
  bf16x8 af;
  AFRAG(af, pA, 0);  y0 = __builtin_amdgcn_mfma_f32_32x32x16_bf16(af, bv[0], y0, 0, 0, 0);
  AFRAG(af, pA, 1);  y0 = __builtin_amdgcn_mfma_f32_32x32x16_bf16(af, bv[1], y0, 0, 0, 0);
  AFRAG(af, pB0, 0); y1 = __builtin_amdgcn_mfma_f32_32x32x16_bf16(af, bv[0], y1, 0, 0, 0);
  AFRAG(af, pB0, 1); y1 = __builtin_amdgcn_mfma_f32_32x32x16_bf16(af, bv[1], y1, 0, 0, 0);
  AFRAG(af, pB1, 0); y1 = __builtin_amdgcn_mfma_f32_32x32x16_bf16(af, bv[2], y1, 0, 0, 0);
  AFRAG(af, pB1, 1); y1 = __builtin_amdgcn_mfma_f32_32x32x16_bf16(af, bv[3], y1, 0, 0, 0);
#undef AFRAG

  if (c31 < 16) {
    #pragma unroll
    for (int r = 0; r < 16; ++r) {
      const int row = (r & 3) + 8 * (r >> 2) + 4 * hi;
      Y[base + (size_t)row * NH + c31]        = f2bf(y0[r]);
      Y[base + (size_t)(32 + row) * NH + c31] = f2bf(y1[r]);
    }
  }
}

// ---------------- launch ------------------------------------------------------
extern "C" void kernel_launch(void* const* d_in, const int* in_sizes, int n_in,
                              void* d_out, int out_size, void* d_ws, size_t ws_size,
                              hipStream_t stream) {
  const float* x  = (const float*)d_in[0];
  const float* Wq = (const float*)d_in[1];
  const float* bq = (const float*)d_in[2];
  const float* Wk = (const float*)d_in[3];
  const float* bk = (const float*)d_in[4];
  const float* Wv = (const float*)d_in[5];
  const float* bv = (const float*)d_in[6];
  const float* Wo = (const float*)d_in[7];
  const float* bo = (const float*)d_in[8];
  float* out = (float*)d_out;

  u16* xb = (u16*)d_ws;                          // [16384][1024]
  u16* Wt = xb + (size_t)MTOK * Ddim;            // 4 x [1024][1024] transposed (q,k,v,o)
  u16* Qb = Wt + 4ull * Ddim * Ddim;
  u16* Kb = Qb + (size_t)MTOK * Ddim;
  u16* Vb = Kb + (size_t)MTOK * Ddim;            // Vt (per-token [nh][hd])
  u16* Yb = xb;                                  // reuse xb after attention

  conv_f32_bf16<<<(MTOK * Ddim / 4 + 255) / 256, 256, 0, stream>>>(x, xb, MTOK * Ddim / 4);

  dim3 tg(Ddim / 32, Ddim / 32);
  conv_transpose_w<<<tg, 256, 0, stream>>>(Wq, Wt + 0ull * Ddim * Ddim);
  conv_transpose_w<<<tg, 256, 0, stream>>>(Wk, Wt + 1ull * Ddim * Ddim);
  conv_transpose_w<<<tg, 256, 0, stream>>>(Wv, Wt + 2ull * Ddim * Ddim);
  conv_transpose_w<<<tg, 256, 0, stream>>>(Wo, Wt + 3ull * Ddim * Ddim);

  // fused QKV: Bt = [Wq^T | Wk^T | Wv^T] (3072 rows); 64 mt x 12 nt = 768 blocks
  gemm256<1><<<dim3(768), 512, 0, stream>>>(xb, Wt, bq, bk, bv, Qb, Kb, Vb);

  attn_mfma<<<MTOK / 4, 256, 0, stream>>>(Qb, Kb, Vb, Yb);

  // output projection: 64 mt x 4 nt = 256 blocks
  gemm256<0><<<dim3(256), 512, 0, stream>>>(Yb, Wt + 3ull * Ddim * Ddim,
                                            bo, bo, bo, out, out, out);
}

// Round 5
// 206.854 us; speedup vs baseline: 1.7211x; 1.0314x over previous
//
#include <hip/hip_runtime.h>
#include <hip/hip_bf16.h>
#include <stdint.h>

typedef unsigned short u16;

#define Bdim 8
#define Ldim 2048
#define Ddim 1024
#define NH 16
#define HD 64
#define MTOK (Bdim*Ldim)   // 16384

typedef __bf16 bf16x8 __attribute__((ext_vector_type(8)));
typedef float  f32x4  __attribute__((ext_vector_type(4)));
typedef float  f32x16 __attribute__((ext_vector_type(16)));

#define AS1 __attribute__((address_space(1)))
#define AS3 __attribute__((address_space(3)))

__device__ __forceinline__ void gload_lds16(const void* g, void* l) {
  __builtin_amdgcn_global_load_lds((const AS1 void*)g, (AS3 void*)l, 16, 0, 0);
}

__device__ __forceinline__ u16 f2bf(float f) {
  uint32_t u = __builtin_bit_cast(uint32_t, f);
  u += 0x7fffu + ((u >> 16) & 1u);   // round-to-nearest-even
  return (u16)(u >> 16);
}
__device__ __forceinline__ uint32_t pkpair(float lo, float hi) {
  return (uint32_t)f2bf(lo) | ((uint32_t)f2bf(hi) << 16);
}

// ---------------- fp32 -> bf16 convert ---------------------------------------
__global__ __launch_bounds__(256) void conv_f32_bf16(const float* __restrict__ in,
                                                     u16* __restrict__ out, int n4) {
  int i = blockIdx.x * 256 + threadIdx.x;
  if (i < n4) {
    float4 v = ((const float4*)in)[i];
    uint32_t w0 = (uint32_t)f2bf(v.x) | ((uint32_t)f2bf(v.y) << 16);
    uint32_t w1 = (uint32_t)f2bf(v.z) | ((uint32_t)f2bf(v.w) << 16);
    ((uint2*)out)[i] = make_uint2(w0, w1);
  }
}

// ---------------- W[K][N] fp32 -> Wt[N][K] bf16 (tiled transpose) ------------
__global__ __launch_bounds__(256) void conv_transpose_w(const float* __restrict__ W,
                                                        u16* __restrict__ Wt) {
  __shared__ float t[32][33];
  int tx = threadIdx.x & 31, ty = threadIdx.x >> 5;
  int k0 = blockIdx.x * 32, n0 = blockIdx.y * 32;
  #pragma unroll
  for (int i = 0; i < 32; i += 8)
    t[ty + i][tx] = W[(size_t)(k0 + ty + i) * Ddim + n0 + tx];
  __syncthreads();
  #pragma unroll
  for (int i = 0; i < 32; i += 8)
    Wt[(size_t)(n0 + ty + i) * Ddim + k0 + tx] = f2bf(t[tx][ty + i]);
}

// ---------------- 256x256 4-slot pipelined GEMM (T1+T2+T3+T4+T5) -------------
// 512 thr = 8 waves (2Mx4N), per-wave 128x64 (acc[8][4]). BK=64, double-buffered
// 128KB LDS. Per K-tile: 4 slots; slot p = {issue 2 stage loads (t+1), counted
// vmcnt (slots 1,3 only), s_barrier, ds_read frags for slot p+1, setprio MFMA
// cluster for slot p}. Fragment regs double-buffered (afA/afB, bf0/bf1).
// Stage order per tile: B0,B1 | B2,B3 | A0,A2 | A1,A3 (chunks = 64-row groups).
// Phase order: (ks0,mh0),(ks1,mh0),(ks0,mh1),(ks1,mh1) -> A chunks {0,2} then {1,3}.
template <int FUSED>
__global__ __launch_bounds__(512, 2) void gemm256(const u16* __restrict__ A,
                                                  const u16* __restrict__ Bt,
                                                  const float* __restrict__ b0p,
                                                  const float* __restrict__ b1p,
                                                  const float* __restrict__ b2p,
                                                  void* __restrict__ o0,
                                                  void* __restrict__ o1,
                                                  void* __restrict__ o2) {
  __shared__ alignas(16) u16 LP[65536];           // 128 KB
  u16* LA = LP;                                    // A: [2 buf][256][64]
  u16* LB = LP + 32768;                            // B: [2 buf][256][64]

  const int tid = threadIdx.x;
  const int wid = tid >> 6, lane = tid & 63;
  const int wr = wid >> 2, wc = wid & 3;           // 2x4 wave grid
  const int fr = lane & 15, fh = lane >> 4;
  const int key = fr & 7;

  const int bid = blockIdx.x;
  const int xcd = bid & 7, idx = bid >> 3;
  const int mt = xcd * 8 + (idx & 7);
  const int nt = idx >> 3;
  const int m0 = mt * 256;
  const int n0g = nt * 256;

  const int srow = wid * 8 + (lane >> 3);
  const int scol = ((lane & 7) ^ (lane >> 3)) * 8; // pre-swizzled source col
  const u16* aG = A  + (size_t)(m0  + srow) * 1024 + scol;
  const u16* bG = Bt + (size_t)(n0g + srow) * 1024 + scol;
  const int ldsW = wid * 512;

  // stage one 64-row chunk slice: MAT 0=A,1=B; chunk S_; K-tile TILE; buffer BUF
#define STG(MAT, S_, TILE, BUF)                                                 \
  gload_lds16(((MAT) ? bG : aG) + (size_t)(TILE) * 64 + (size_t)(S_) * 65536,   \
              ((MAT) ? LB : LA) + (BUF) * 16384 + (S_) * 4096 + ldsW)

#define RD_AF(DST, BUF, KS, MH) do {                                            \
    const u16* base_ = LA + (BUF) * 16384;                                      \
    const int p_ = (((KS) * 4 + fh) ^ key) * 8;                                 \
    _Pragma("unroll")                                                           \
    for (int mm_ = 0; mm_ < 4; ++mm_)                                           \
      DST[mm_] = *(const bf16x8*)(base_ +                                       \
                   (wr * 128 + (MH) * 64 + mm_ * 16 + fr) * 64 + p_);           \
  } while (0)
#define RD_BF(DST, BUF, KS) do {                                                \
    const u16* base_ = LB + (BUF) * 16384;                                      \
    const int p_ = (((KS) * 4 + fh) ^ key) * 8;                                 \
    _Pragma("unroll")                                                           \
    for (int n_ = 0; n_ < 4; ++n_)                                              \
      DST[n_] = *(const bf16x8*)(base_ + (wc * 64 + n_ * 16 + fr) * 64 + p_);   \
  } while (0)
#define MFMA16(AF, BF, MH) do {                                                 \
    __builtin_amdgcn_s_setprio(1);                                              \
    _Pragma("unroll")                                                           \
    for (int mm_ = 0; mm_ < 4; ++mm_)                                           \
      _Pragma("unroll")                                                         \
      for (int n_ = 0; n_ < 4; ++n_)                                            \
        acc[(MH) * 4 + mm_][n_] = __builtin_amdgcn_mfma_f32_16x16x32_bf16(      \
            AF[mm_], BF[n_], acc[(MH) * 4 + mm_][n_], 0, 0, 0);                 \
    __builtin_amdgcn_s_setprio(0);                                              \
  } while (0)
#define WAITV(N) asm volatile("s_waitcnt vmcnt(" #N ")" ::: "memory")
#define BAR() __builtin_amdgcn_s_barrier()

  f32x4 acc[8][4] = {};
  bf16x8 afA[4], afB[4], bf0[4], bf1[4];

  // prologue: tile 0 -> buf 0 (order B0..B3, A0, A2, A1, A3)
  STG(1,0,0,0); STG(1,1,0,0); STG(1,2,0,0); STG(1,3,0,0);
  STG(0,0,0,0); STG(0,2,0,0); STG(0,1,0,0); STG(0,3,0,0);
  WAITV(2); BAR();                      // B*, A0, A2 of tile 0 resident
  RD_AF(afA, 0, 0, 0); RD_BF(bf0, 0, 0);  // F[0]^0

  #pragma unroll 1
  for (int t = 0; t < 15; ++t) {
    const int cur = t & 1, nxt = cur ^ 1;
    // slot0: MFMA F0; read F1 (ks1,mh0 + bf1); stage B0,B1(t+1)
    STG(1,0,t+1,nxt); STG(1,1,t+1,nxt);
    BAR();
    RD_AF(afB, cur, 1, 0); RD_BF(bf1, cur, 1);
    MFMA16(afA, bf0, 0);
    // slot1: MFMA F1; read F2 (ks0,mh1); stage B2,B3; vmcnt(4) retires A1,A3(t)
    STG(1,2,t+1,nxt); STG(1,3,t+1,nxt);
    WAITV(4); BAR();
    RD_AF(afA, cur, 0, 1);
    MFMA16(afB, bf1, 0);
    // slot2: MFMA F2; read F3 (ks1,mh1); stage A0,A2(t+1)
    STG(0,0,t+1,nxt); STG(0,2,t+1,nxt);
    BAR();
    RD_AF(afB, cur, 1, 1);
    MFMA16(afA, bf0, 1);
    // slot3: MFMA F3; read F0^{t+1} from nxt (chunks 0,2 + B done after vmcnt(2));
    //        stage A1,A3(t+1) first so the wait stays counted
    STG(0,1,t+1,nxt); STG(0,3,t+1,nxt);
    WAITV(2); BAR();
    RD_AF(afA, nxt, 0, 0); RD_BF(bf0, nxt, 0);
    MFMA16(afB, bf1, 1);
  }
  // epilogue tile 15 (buf 1): F0 already in afA/bf0
  RD_AF(afB, 1, 1, 0); RD_BF(bf1, 1, 1);
  MFMA16(afA, bf0, 0);
  WAITV(0); BAR();                      // A1,A3 of tile 15
  RD_AF(afA, 1, 0, 1);
  MFMA16(afB, bf1, 0);
  RD_AF(afB, 1, 1, 1);
  MFMA16(afA, bf0, 1);
  MFMA16(afB, bf1, 1);

  __syncthreads();                      // LDS reuse below (Ct overlaps LA/LB)

  if (FUSED) {
    const int which = nt >> 2;                    // 0 Q, 1 K, 2 V
    const int n0l = (nt & 3) * 256;
    const float* bias = which == 0 ? b0p : which == 1 ? b1p : b2p;
    u16* Out = (u16*)(which == 0 ? o0 : which == 1 ? o1 : o2);
    u16* Ct = LP;                                 // [4 regions][128][72] u16
    #pragma unroll 1
    for (int h = 0; h < 2; ++h) {
      if (h) __syncthreads();
      if (wr == h) {
        #pragma unroll
        for (int n = 0; n < 4; ++n) {
          float bvv = bias[n0l + wc * 64 + n * 16 + fr];
          #pragma unroll
          for (int m = 0; m < 8; ++m)
            #pragma unroll
            for (int r = 0; r < 4; ++r)
              Ct[wc * 9216 + (m * 16 + fh * 4 + r) * 72 + n * 16 + fr] =
                  f2bf(acc[m][n][r] + bvv);
        }
      }
      __syncthreads();
      if (which != 2) {
        #pragma unroll
        for (int j = 0; j < 8; ++j) {
          int r = j * 16 + (tid >> 5), c8 = tid & 31;
          uint4 v = *(const uint4*)(Ct + (c8 >> 3) * 9216 + r * 72 + (c8 & 7) * 8);
          *(uint4*)(Out + (size_t)(m0 + h * 128 + r) * Ddim + n0l + c8 * 8) = v;
        }
      } else {
        // V per-token transposed: Vt[i=d&15][k=d>>4]
        #pragma unroll
        for (int j = 0; j < 4; ++j) {
          int q = j * 512 + tid, r = q >> 4, i = q & 15;
          u16 tmp[16];
          #pragma unroll
          for (int jj = 0; jj < 16; ++jj) {
            int c = i + 16 * jj;
            tmp[jj] = Ct[(c >> 6) * 9216 + r * 72 + (c & 63)];
          }
          u16* dst = Out + (size_t)(m0 + h * 128 + r) * Ddim + i * 64 + (n0l >> 4);
          *(uint4*)dst = *(uint4*)tmp;
          *(uint4*)(dst + 8) = *(uint4*)(tmp + 8);
        }
      }
      __syncthreads();
    }
  } else {
    float* Cf = (float*)LP;                       // [2 regions][128][68] f32
    float* Out = (float*)o0;
    #pragma unroll 1
    for (int h = 0; h < 4; ++h) {
      if (h) __syncthreads();
      if (wr == (h >> 1) && (wc >> 1) == (h & 1)) {
        #pragma unroll
        for (int n = 0; n < 4; ++n) {
          float bvv = b0p[n0g + (h & 1) * 128 + (wc & 1) * 64 + n * 16 + fr];
          #pragma unroll
          for (int m = 0; m < 8; ++m)
            #pragma unroll
            for (int r = 0; r < 4; ++r)
              Cf[(wc & 1) * 8704 + (m * 16 + fh * 4 + r) * 68 + n * 16 + fr] =
                  acc[m][n][r] + bvv;
        }
      }
      __syncthreads();
      #pragma unroll
      for (int j = 0; j < 8; ++j) {
        int r = j * 16 + (tid >> 5), c4 = tid & 31;
        float4 v = *(const float4*)(Cf + (c4 >> 4) * 8704 + r * 68 + (c4 & 15) * 4);
        *(float4*)(Out + (size_t)(m0 + (h >> 1) * 128 + r) * Ddim +
                   n0g + (h & 1) * 128 + c4 * 4) = v;
      }
      __syncthreads();
    }
  }
#undef STG
#undef RD_AF
#undef RD_BF
#undef MFMA16
#undef WAITV
#undef BAR
}

// ---------------- per-token attention via MFMA (unchanged, verified) ---------
__global__ __launch_bounds__(256) void attn_mfma(const u16* __restrict__ Q,
                                                 const u16* __restrict__ Kb,
                                                 const u16* __restrict__ Vt,
                                                 u16* __restrict__ Y) {
  const int wid = threadIdx.x >> 6, lane = threadIdx.x & 63;
  const int tok = blockIdx.x * 4 + wid;
  const size_t base = (size_t)tok * Ddim;
  const int hi = lane >> 5, c31 = lane & 31;

  const bf16x8 kf0 = *(const bf16x8*)(Kb + base + (size_t)c31 * NH + hi * 8);
  const bf16x8 kf1 = *(const bf16x8*)(Kb + base + (size_t)(32 + c31) * NH + hi * 8);
  const bf16x8 qf0 = *(const bf16x8*)(Q  + base + (size_t)c31 * NH + hi * 8);
  const bf16x8 qf1 = *(const bf16x8*)(Q  + base + (size_t)(32 + c31) * NH + hi * 8);
  bf16x8 bv[4];
  #pragma unroll
  for (int c = 0; c < 4; ++c)
    bv[c] = *(const bf16x8*)(Vt + base + (size_t)(lane & 15) * HD + c * 16 + hi * 8);

  const f32x16 z = {};
  f32x16 s00 = __builtin_amdgcn_mfma_f32_32x32x16_bf16(kf0, qf0, z, 0, 0, 0);
  f32x16 s01 = __builtin_amdgcn_mfma_f32_32x32x16_bf16(kf0, qf1, z, 0, 0, 0);
  f32x16 s11 = __builtin_amdgcn_mfma_f32_32x32x16_bf16(kf1, qf1, z, 0, 0, 0);

  float a[16], b0[16], b1[16];
  float mA = -3e38f, mB = -3e38f;
  #pragma unroll
  for (int r = 0; r < 16; ++r) {
    const int kl = (r & 3) + 8 * (r >> 2) + 4 * hi;
    const bool keep = kl <= c31;
    float v00 = fmaf(s00[r], 0.25f, 1e-6f);
    float v01 = fmaf(s01[r], 0.25f, 1e-6f);
    float v11 = fmaf(s11[r], 0.25f, 1e-6f);
    a[r]  = keep ? v00 : -3e38f;
    b0[r] = v01;
    b1[r] = keep ? v11 : -3e38f;
    mA = fmaxf(mA, a[r]);
    mB = fmaxf(mB, fmaxf(b0[r], b1[r]));
  }
  mA = fmaxf(mA, __shfl_xor(mA, 32, 64));
  mB = fmaxf(mB, __shfl_xor(mB, 32, 64));
  float sA = 0.f, sB = 0.f;
  #pragma unroll
  for (int r = 0; r < 16; ++r) {
    a[r]  = __expf(a[r]  - mA);  sA += a[r];
    b0[r] = __expf(b0[r] - mB);
    b1[r] = __expf(b1[r] - mB);  sB += b0[r] + b1[r];
  }
  sA += __shfl_xor(sA, 32, 64);
  sB += __shfl_xor(sB, 32, 64);
  const float iA = __builtin_amdgcn_rcpf(sA);
  const float iB = __builtin_amdgcn_rcpf(sB);

  uint32_t pA[4][2], pB0[4][2], pB1[4][2];
  #pragma unroll
  for (int m = 0; m < 4; ++m)
    #pragma unroll
    for (int t = 0; t < 2; ++t) {
      pA [m][t] = pkpair(a [4*m+2*t] * iA, a [4*m+2*t+1] * iA);
      pB0[m][t] = pkpair(b0[4*m+2*t] * iB, b0[4*m+2*t+1] * iB);
      pB1[m][t] = pkpair(b1[4*m+2*t] * iB, b1[4*m+2*t+1] * iB);
    }

#define AFRAG(dst, src, cp) do {                                              \
    uint32_t k0_ = hi ? src[2*(cp)+1][0] : src[2*(cp)][0];                    \
    uint32_t k1_ = hi ? src[2*(cp)+1][1] : src[2*(cp)][1];                    \
    uint32_t s0_ = hi ? src[2*(cp)][0]   : src[2*(cp)+1][0];                  \
    uint32_t s1_ = hi ? src[2*(cp)][1]   : src[2*(cp)+1][1];                  \
    uint32_t r0_ = (uint32_t)__shfl_xor((int)s0_, 32, 64);                    \
    uint32_t r1_ = (uint32_t)__shfl_xor((int)s1_, 32, 64);                    \
    union { uint32_t w[4]; bf16x8 v; } u_;                                    \
    u_.w[0] = hi ? r0_ : k0_;  u_.w[1] = hi ? r1_ : k1_;                      \
    u_.w[2] = hi ? k0_ : r0_;  u_.w[3] = hi ? k1_ : r1_;                      \
    dst = u_.v;                                                               \
  } while (0)

  f32x16 y0 = {}, y1 = {};
  bf16x8 af;
  AFRAG(af, pA, 0);  y0 = __builtin_amdgcn_mfma_f32_32x32x16_bf16(af, bv[0], y0, 0, 0, 0);
  AFRAG(af, pA, 1);  y0 = __builtin_amdgcn_mfma_f32_32x32x16_bf16(af, bv[1], y0, 0, 0, 0);
  AFRAG(af, pB0, 0); y1 = __builtin_amdgcn_mfma_f32_32x32x16_bf16(af, bv[0], y1, 0, 0, 0);
  AFRAG(af, pB0, 1); y1 = __builtin_amdgcn_mfma_f32_32x32x16_bf16(af, bv[1], y1, 0, 0, 0);
  AFRAG(af, pB1, 0); y1 = __builtin_amdgcn_mfma_f32_32x32x16_bf16(af, bv[2], y1, 0, 0, 0);
  AFRAG(af, pB1, 1); y1 = __builtin_amdgcn_mfma_f32_32x32x16_bf16(af, bv[3], y1, 0, 0, 0);
#undef AFRAG

  if (c31 < 16) {
    #pragma unroll
    for (int r = 0; r < 16; ++r) {
      const int row = (r & 3) + 8 * (r >> 2) + 4 * hi;
      Y[base + (size_t)row * NH + c31]        = f2bf(y0[r]);
      Y[base + (size_t)(32 + row) * NH + c31] = f2bf(y1[r]);
    }
  }
}

// ---------------- launch ------------------------------------------------------
extern "C" void kernel_launch(void* const* d_in, const int* in_sizes, int n_in,
                              void* d_out, int out_size, void* d_ws, size_t ws_size,
                              hipStream_t stream) {
  const float* x  = (const float*)d_in[0];
  const float* Wq = (const float*)d_in[1];
  const float* bq = (const float*)d_in[2];
  const float* Wk = (const float*)d_in[3];
  const float* bk = (const float*)d_in[4];
  const float* Wv = (const float*)d_in[5];
  const float* bv = (const float*)d_in[6];
  const float* Wo = (const float*)d_in[7];
  const float* bo = (const float*)d_in[8];
  float* out = (float*)d_out;

  u16* xb = (u16*)d_ws;                          // [16384][1024]
  u16* Wt = xb + (size_t)MTOK * Ddim;            // 4 x [1024][1024] transposed (q,k,v,o)
  u16* Qb = Wt + 4ull * Ddim * Ddim;
  u16* Kb = Qb + (size_t)MTOK * Ddim;
  u16* Vb = Kb + (size_t)MTOK * Ddim;            // Vt (per-token [nh][hd])
  u16* Yb = xb;                                  // reuse xb after attention

  conv_f32_bf16<<<(MTOK * Ddim / 4 + 255) / 256, 256, 0, stream>>>(x, xb, MTOK * Ddim / 4);

  dim3 tg(Ddim / 32, Ddim / 32);
  conv_transpose_w<<<tg, 256, 0, stream>>>(Wq, Wt + 0ull * Ddim * Ddim);
  conv_transpose_w<<<tg, 256, 0, stream>>>(Wk, Wt + 1ull * Ddim * Ddim);
  conv_transpose_w<<<tg, 256, 0, stream>>>(Wv, Wt + 2ull * Ddim * Ddim);
  conv_transpose_w<<<tg, 256, 0, stream>>>(Wo, Wt + 3ull * Ddim * Ddim);

  // fused QKV: Bt = [Wq^T | Wk^T | Wv^T] (3072 rows); 64 mt x 12 nt = 768 blocks
  gemm256<1><<<dim3(768), 512, 0, stream>>>(xb, Wt, bq, bk, bv, Qb, Kb, Vb);

  attn_mfma<<<MTOK / 4, 256, 0, stream>>>(Qb, Kb, Vb, Yb);

  // output projection: 64 mt x 4 nt = 256 blocks
  gemm256<0><<<dim3(256), 512, 0, stream>>>(Yb, Wt + 3ull * Ddim * Ddim,
                                            bo, bo, bo, out, out, out);
}